// Round 8
// baseline (273.361 us; speedup 1.0000x reference)
//
#include <hip/hip_runtime.h>

// 8x8 block DCT: C = A * B * A^T per non-overlapping block.
// R2:  LDS-staged coalesced nt stores, XOR-swizzle (0 bank conflicts);
//      nt stores keep input L3-resident (FETCH = 65.6 MB = half input).
// R7:  persistent 128-thread wgs, software-pipelined loads, even/odd
//      butterfly (VALU 17%->6%, VGPR 92).
// R8:  lgkm-only barriers (no vmcnt drains) -> flat 83.5us.
// R9:  halved LDS + 8 wg/CU, but split stores by C-ROWS -> rows 0-3 of all
//      blocks stored to a CONTIGUOUS half of the output (block-major layout)
//      -> wrong placement, absmax 468. LAYOUT BUG, not a perf datapoint.
// R10: split by BLOCKS instead: sub-phase p stages the FULL outputs of the
//      64 blocks owned by threads [p*64,(p+1)*64) -> contiguous 16 KiB of
//      output (floats [p*4096,(p+1)*4096) of the block-row). This is exactly
//      R2's verified half-phase layout (write f^(tl&15), read f4^((f4>>4)&15),
//      0 conflicts) with a 16 KiB buffer. c-pin before the phase loop keeps
//      compute (and thus loads) above the first barrier (R2's sinking bug).
//      grid=2048, ITERS=2, launch_bounds(128,4) -> 8 wg/CU = 4 waves/SIMD.

typedef float f32x4 __attribute__((ext_vector_type(4)));

#define ITERS 2

// Barrier that does NOT drain vmcnt: LDS-visibility only.
__device__ __forceinline__ void lds_barrier() {
    asm volatile("s_waitcnt lgkmcnt(0)" ::: "memory");
    __builtin_amdgcn_s_barrier();
}

__global__ __launch_bounds__(128, 4) void dct8x8_kernel(const float* __restrict__ x,
                                                        float* __restrict__ out) {
    constexpr float A[8][8] = {
        { 0.35355339059327373f,  0.35355339059327373f,  0.35355339059327373f,  0.35355339059327373f,
          0.35355339059327373f,  0.35355339059327373f,  0.35355339059327373f,  0.35355339059327373f},
        { 0.49039264020161522f,  0.41573480615127262f,  0.27778511650980114f,  0.09754516100806417f,
         -0.09754516100806417f, -0.27778511650980114f, -0.41573480615127262f, -0.49039264020161522f},
        { 0.46193976625564337f,  0.19134171618254492f, -0.19134171618254492f, -0.46193976625564337f,
         -0.46193976625564337f, -0.19134171618254492f,  0.19134171618254492f,  0.46193976625564337f},
        { 0.41573480615127262f, -0.09754516100806417f, -0.49039264020161522f, -0.27778511650980114f,
          0.27778511650980114f,  0.49039264020161522f,  0.09754516100806417f, -0.41573480615127262f},
        { 0.35355339059327373f, -0.35355339059327373f, -0.35355339059327373f,  0.35355339059327373f,
          0.35355339059327373f, -0.35355339059327373f, -0.35355339059327373f,  0.35355339059327373f},
        { 0.27778511650980114f, -0.49039264020161522f,  0.09754516100806417f,  0.41573480615127262f,
         -0.41573480615127262f, -0.09754516100806417f,  0.49039264020161522f, -0.27778511650980114f},
        { 0.19134171618254492f, -0.46193976625564337f,  0.46193976625564337f, -0.19134171618254492f,
         -0.19134171618254492f,  0.46193976625564337f, -0.46193976625564337f,  0.19134171618254492f},
        { 0.09754516100806417f, -0.27778511650980114f,  0.41573480615127262f, -0.49039264020161522f,
          0.49039264020161522f, -0.41573480615127262f,  0.27778511650980114f, -0.09754516100806417f},
    };

    __shared__ f32x4 lds4[1024];  // 16 KiB: 64 full block outputs per sub-phase

    const int tl = threadIdx.x;            // 0..127 == block-column bj
    const int g0 = blockIdx.x * ITERS;     // first block-row (global)
    const int n  = g0 >> 7;                // image index
    const int bi = g0 & 127;               // block-row within image

    // rows bi*8 .. bi*8+7 of image n, this thread's 8-float column window
    const float* src = x + (((size_t)n << 20) + ((size_t)bi << 13) + (tl << 3));

    // Prologue: load the first block-row's 8 rows (16 x dwordx4).
    f32x4 r[16];
#pragma unroll
    for (int j = 0; j < 8; ++j) {
        r[2 * j]     = *reinterpret_cast<const f32x4*>(src + j * 1024);
        r[2 * j + 1] = *reinterpret_cast<const f32x4*>(src + j * 1024 + 4);
    }

    for (int it = 0; it < ITERS; ++it) {
        // Stage 1 (butterfly): Mt[j][m] = sum_l B[j][l] * A[m][l].
        float Mt[64];
#pragma unroll
        for (int j = 0; j < 8; ++j) {
            const float b0 = r[2*j].x, b1 = r[2*j].y, b2 = r[2*j].z, b3 = r[2*j].w;
            const float b4 = r[2*j+1].x, b5 = r[2*j+1].y, b6 = r[2*j+1].z, b7 = r[2*j+1].w;
            const float u0 = b0 + b7, u1 = b1 + b6, u2 = b2 + b5, u3 = b3 + b4;
            const float v0 = b0 - b7, v1 = b1 - b6, v2 = b2 - b5, v3 = b3 - b4;
#pragma unroll
            for (int m = 0; m < 8; m += 2) {
                float e = u0 * A[m][0];
                e = fmaf(u1, A[m][1], e);
                e = fmaf(u2, A[m][2], e);
                e = fmaf(u3, A[m][3], e);
                Mt[j * 8 + m] = e;
                float o = v0 * A[m + 1][0];
                o = fmaf(v1, A[m + 1][1], o);
                o = fmaf(v2, A[m + 1][2], o);
                o = fmaf(v3, A[m + 1][3], o);
                Mt[j * 8 + m + 1] = o;
            }
        }

        // Pipeline: r is dead -> issue next block-row's loads; they stay in
        // flight across the lgkm-only barriers until next stage 1.
        if (it + 1 < ITERS) {
            const float* nsrc = src + (it + 1) * 8192;
#pragma unroll
            for (int j = 0; j < 8; ++j) {
                r[2 * j]     = *reinterpret_cast<const f32x4*>(nsrc + j * 1024);
                r[2 * j + 1] = *reinterpret_cast<const f32x4*>(nsrc + j * 1024 + 4);
            }
        }

        // Stage 2 (butterfly over j): c[i][m] = sum_j A[i][j] * Mt[j][m].
        float c[64];
#pragma unroll
        for (int m = 0; m < 8; ++m) {
            const float u0 = Mt[0*8+m] + Mt[7*8+m];
            const float u1 = Mt[1*8+m] + Mt[6*8+m];
            const float u2 = Mt[2*8+m] + Mt[5*8+m];
            const float u3 = Mt[3*8+m] + Mt[4*8+m];
            const float v0 = Mt[0*8+m] - Mt[7*8+m];
            const float v1 = Mt[1*8+m] - Mt[6*8+m];
            const float v2 = Mt[2*8+m] - Mt[5*8+m];
            const float v3 = Mt[3*8+m] - Mt[4*8+m];
#pragma unroll
            for (int i = 0; i < 8; i += 2) {
                float e = u0 * A[i][0];
                e = fmaf(u1, A[i][1], e);
                e = fmaf(u2, A[i][2], e);
                e = fmaf(u3, A[i][3], e);
                c[i * 8 + m] = e;
                float o = v0 * A[i + 1][0];
                o = fmaf(v1, A[i + 1][1], o);
                o = fmaf(v2, A[i + 1][2], o);
                o = fmaf(v3, A[i + 1][3], o);
                c[(i + 1) * 8 + m] = o;
            }
        }

        // Pin c: compute (and thus the loads feeding it) cannot sink into the
        // guarded half-phase bodies below (R2's serialization bug).
#pragma unroll
        for (int i = 0; i < 64; ++i) asm volatile("" : "+v"(c[i]));

        // Two sub-phases by BLOCK ownership: phase p = blocks of threads
        // [p*64,(p+1)*64) -> output floats [p*4096,(p+1)*4096) (contiguous).
        float* dsto = out + ((size_t)(g0 + it) << 13);
#pragma unroll
        for (int p = 0; p < 2; ++p) {
            if ((tl >> 6) == p) {
                // Stage my full block: 16 float4s at f0=(tl&63)*16 + i*2,
                // XOR (tl&15) within my 16-slot group (R2's verified swizzle).
                const int b = tl & 63;
#pragma unroll
                for (int i = 0; i < 8; ++i) {
                    const int f0 = b * 16 + i * 2;
                    f32x4 w0; w0.x = c[i*8+0]; w0.y = c[i*8+1]; w0.z = c[i*8+2]; w0.w = c[i*8+3];
                    f32x4 w1; w1.x = c[i*8+4]; w1.y = c[i*8+5]; w1.z = c[i*8+6]; w1.w = c[i*8+7];
                    lds4[f0 ^ (tl & 15)]       = w0;
                    lds4[(f0 + 1) ^ (tl & 15)] = w1;
                }
            }
            lds_barrier();  // LDS writes visible; prefetch loads stay in flight

            // Coalesced nontemporal store: 1024 float4 = 16 KiB contiguous;
            // 128 threads x 16 B = 2 KiB per instruction. Writer of logical
            // f4 was thread (f4>>4) (mod 64) -> stored at f4 ^ ((f4>>4)&15).
            f32x4* dst4 = reinterpret_cast<f32x4*>(dsto + p * 4096);
#pragma unroll
            for (int s = 0; s < 8; ++s) {
                const int f4 = s * 128 + tl;
                __builtin_nontemporal_store(lds4[f4 ^ ((f4 >> 4) & 15)], dst4 + f4);
            }
            // LDS reuse needs only the ds_read half retired (lgkm).
            lds_barrier();
        }
    }
}

extern "C" void kernel_launch(void* const* d_in, const int* in_sizes, int n_in,
                              void* d_out, int out_size, void* d_ws, size_t ws_size,
                              hipStream_t stream) {
    const float* x = (const float*)d_in[0];
    float* out = (float*)d_out;

    const int nblocks = out_size / 64;            // 524288 8x8 blocks
    const int ngroups = nblocks / 128;            // 4096 block-rows
    const int grid = ngroups / ITERS;             // 2048 workgroups, 8/CU resident
    dct8x8_kernel<<<grid, 128, 0, stream>>>(x, out);
}